// Round 13
// baseline (32.428 us; speedup 1.0000x reference)
//
#include <hip/hip_runtime.h>
#include <hip/hip_bf16.h>

// Problem constants (fixed by reference): B=8, T=2048, C=64
#define B_ 8
#define T_ 2048
#define LOG2E 1.4426950408889634f

typedef _Float16 half8 __attribute__((ext_vector_type(8)));
typedef _Float16 half4 __attribute__((ext_vector_type(4)));
typedef float f32x4 __attribute__((ext_vector_type(4)));

#define MFMA16(A, Bv, Cv) __builtin_amdgcn_mfma_f32_16x16x32_f16((A), (Bv), (Cv), 0, 0, 0)

__device__ inline float xexp2(float x)
{
    float r;
    asm("v_exp_f32 %0, %1" : "=v"(r) : "v"(x));
    return r;
}

// ---------------------------------------------------------------------------
// Kernel 0: pre-pack weights. W [k][d] fp32 -> Wp [mat][d][k] f16.
// ---------------------------------------------------------------------------
__global__ __launch_bounds__(256) void prepack_kernel(
    const float* __restrict__ WM, const float* __restrict__ WN,
    const float* __restrict__ WV, _Float16* __restrict__ Wp)
{
    const int idx = blockIdx.x * 256 + threadIdx.x;   // [0, 12288)
    const int m = idx >> 12;
    const int r = idx & 4095;
    const int d = r >> 6;
    const int k = r & 63;
    const float* W = (m == 0) ? WM : (m == 1) ? WN : WV;
    Wp[m * 4096 + d * 64 + k] = (_Float16)W[k * 64 + d];
}

// ---------------------------------------------------------------------------
// Kernel 1: MFMA projections -> fragment-major Q/K/V layouts, ALL stores
// wave-coalesced. Q and K both computed with swapped MFMA operands
// (lane = t, regs = contiguous d) and stored in the SAME fragment-major
// tile layout: [16-row tile][plane p][row][8d] where plane p covers
// d in [8p, 8p+7] (p = ((d0>>5)<<2)|((d0>>3)&3), tile = 128 half8).
// V unswapped (lane = d, regs = contiguous sigma-permuted key slots),
// R11-verified layout. 3 x 8B coalesced stores per thread.
// ---------------------------------------------------------------------------
__global__ __launch_bounds__(256) void proj_kernel(
    const float* __restrict__ F, const _Float16* __restrict__ Wp,
    _Float16* __restrict__ Qf, _Float16* __restrict__ Kf,
    _Float16* __restrict__ Vf)
{
    const int lane = threadIdx.x & 63;
    const int dt   = threadIdx.x >> 6;            // 0..3 = d-tile
    const int ql = lane & 15;
    const int g  = lane >> 4;
    const int blk = blockIdx.x;                   // 0..1023
    const int b   = blk & 7;                      // XCD-affine batch
    const int rt  = blk >> 3;                     // 0..127 row-tile in batch
    const int rowbase = b * T_ + rt * 16;

    const float* fr = F + (size_t)(rowbase + ql) * 64;
    const f32x4 v00 = *(const f32x4*)(fr + 8 * g);
    const f32x4 v01 = *(const f32x4*)(fr + 8 * g + 4);
    const f32x4 v10 = *(const f32x4*)(fr + 32 + 8 * g);
    const f32x4 v11 = *(const f32x4*)(fr + 32 + 8 * g + 4);
    half8 af0, af1;
#pragma unroll
    for (int j = 0; j < 4; ++j) {
        af0[j]     = (_Float16)v00[j];
        af0[4 + j] = (_Float16)v01[j];
        af1[j]     = (_Float16)v10[j];
        af1[4 + j] = (_Float16)v11[j];
    }

    const half8* wq = (const half8*)(Wp);
    const half8* wk = (const half8*)(Wp + 4096);
    const half8* wv = (const half8*)(Wp + 8192);

    const int fi = (dt * 16 + ql) * 8;
    f32x4 z = {0.f, 0.f, 0.f, 0.f};
    // Q, K swapped: lane = t (row), regs = d
    f32x4 accQ = MFMA16(wq[fi + g], af0, z);
    accQ = MFMA16(wq[fi + 4 + g], af1, accQ);
    f32x4 accK = MFMA16(wk[fi + g], af0, z);
    accK = MFMA16(wk[fi + 4 + g], af1, accK);
    // V unswapped: lane = d, regs = key
    f32x4 accV = MFMA16(af0, wv[fi + g], z);
    accV = MFMA16(af1, wv[fi + 4 + g], accV);

    const int d0 = dt * 16 + 4 * g;
    const int p  = ((d0 >> 5) << 2) | ((d0 >> 3) & 3);
    const size_t tbase = (((size_t)b * 128 + rt) * 8 + p) * 128 + ql * 8 + (d0 & 7);
    // ---- Q store (fragment-major, pre-scaled by LOG2E) ----
    {
        half4 qs;
#pragma unroll
        for (int r = 0; r < 4; ++r) qs[r] = (_Float16)(accQ[r] * LOG2E);
        *(half4*)(Qf + tbase) = qs;
    }
    // ---- K store (fragment-major) ----
    {
        half4 ks;
#pragma unroll
        for (int r = 0; r < 4; ++r) ks[r] = (_Float16)accK[r];
        *(half4*)(Kf + tbase) = ks;
    }
    // ---- V store: d = dt*16+ql, keys -> cp = 8g + 4*(rt&1) + r (contig) ----
    {
        half4 vs;
#pragma unroll
        for (int r = 0; r < 4; ++r) vs[r] = (_Float16)accV[r];
        const int kt5 = rt >> 1;
        const int cp0 = 8 * g + 4 * (rt & 1);
        *(half4*)(Vf + ((((size_t)b * 64 + kt5) * 4 + dt) * 16 + ql) * 32 + cp0) = vs;
    }
}

// One q-tile's 32-key step (R10/R11/R12-verified, flattened named registers).
#define PROC(qf0, qf1, a0, a1, a2, a3, mr, ls)                               \
    do {                                                                     \
        f32x4 s0 = {0.f, 0.f, 0.f, 0.f};                                     \
        f32x4 s1 = {0.f, 0.f, 0.f, 0.f};                                     \
        s0 = MFMA16(k0lo, qf0, s0);                                          \
        s0 = MFMA16(k0hi, qf1, s0);                                          \
        s1 = MFMA16(k1lo, qf0, s1);                                          \
        s1 = MFMA16(k1hi, qf1, s1);                                          \
        const float p0 = s0[0], p1 = s0[1], p2 = s0[2], p3 = s0[3];          \
        const float p4 = s1[0], p5 = s1[1], p6 = s1[2], p7 = s1[3];          \
        const float q0_ = fmaxf(fmaxf(p0, p1), p2);                          \
        const float q1_ = fmaxf(fmaxf(p3, p4), p5);                          \
        const float q2_ = fmaxf(fmaxf(p6, p7), q0_);                         \
        const float pm  = fmaxf(q1_, q2_);                                   \
        if (__any(pm - mr > 8.0f)) {                                         \
            float pmw = fmaxf(pm, __shfl_xor(pm, 16));                       \
            pmw = fmaxf(pmw, __shfl_xor(pmw, 32));                           \
            const float mnew = fmaxf(mr, pmw);                               \
            const float fac  = xexp2(mr - mnew);                             \
            mr = mnew;                                                       \
            ls *= fac;                                                       \
            const int lg = 4 * ((threadIdx.x & 63) >> 4);                    \
            const int lb = (threadIdx.x & 48);                               \
            const float f0 = __shfl(fac, lb | (lg + 0));                     \
            const float f1 = __shfl(fac, lb | (lg + 1));                     \
            const float f2 = __shfl(fac, lb | (lg + 2));                     \
            const float f3 = __shfl(fac, lb | (lg + 3));                     \
            a0[0] *= f0; a0[1] *= f1; a0[2] *= f2; a0[3] *= f3;              \
            a1[0] *= f0; a1[1] *= f1; a1[2] *= f2; a1[3] *= f3;              \
            a2[0] *= f0; a2[1] *= f1; a2[2] *= f2; a2[3] *= f3;              \
            a3[0] *= f0; a3[1] *= f1; a3[2] *= f2; a3[3] *= f3;              \
        }                                                                    \
        const float e0 = xexp2(p0 - mr), e1 = xexp2(p1 - mr);                \
        const float e2 = xexp2(p2 - mr), e3 = xexp2(p3 - mr);                \
        const float e4 = xexp2(p4 - mr), e5 = xexp2(p5 - mr);                \
        const float e6 = xexp2(p6 - mr), e7 = xexp2(p7 - mr);                \
        ls += ((e0 + e1) + (e2 + e3)) + ((e4 + e5) + (e6 + e7));             \
        half8 pav;                                                           \
        pav[0] = (_Float16)e0; pav[1] = (_Float16)e1;                        \
        pav[2] = (_Float16)e2; pav[3] = (_Float16)e3;                        \
        pav[4] = (_Float16)e4; pav[5] = (_Float16)e5;                        \
        pav[6] = (_Float16)e6; pav[7] = (_Float16)e7;                        \
        a0 = MFMA16(pav, v0, a0);                                            \
        a1 = MFMA16(pav, v1, a1);                                            \
        a2 = MFMA16(pav, v2, a2);                                            \
        a3 = MFMA16(pav, v3, a3);                                            \
    } while (0)

// ---------------------------------------------------------------------------
// Kernel 2: flash attention. Grid = 256 blocks x 8 waves (512 thr) -- R10's
// best-traffic structure: block = 64 q-rows, wave = ALL FOUR q-tiles x one
// 256-key split (512 KB K/V per CU, the full-utilization floor), plus R12's
// register prefetch. launch_bounds(512,1): ~190 live VGPR, no spill;
// 1 block/CU (LDS 139 KB), 2 waves/SIMD.
// ---------------------------------------------------------------------------
__global__ __launch_bounds__(512, 1) void attn_kernel(
    const _Float16* __restrict__ Qf, const _Float16* __restrict__ Kf,
    const _Float16* __restrict__ Vf, const float* __restrict__ F,
    float* __restrict__ out)
{
    __shared__ float Ol[8][64][68];    // 139 KB: [split][row][d]
    __shared__ float Ml[8][64];
    __shared__ float Ll[8][64];

    const int lane = threadIdx.x & 63;
    const int wid  = threadIdx.x >> 6;           // 0..7 = key-split
    const int blk  = blockIdx.x;                 // 0..255
    const int b    = blk & 7;                    // XCD-affine batch
    const int tile = blk >> 3;                   // 0..31
    const int ql = lane & 15;
    const int g  = lane >> 4;

    const half8* QfB = (const half8*)Qf + (size_t)b * 16384;  // 128 tiles * 128
    const half8* KfB = (const half8*)Kf + (size_t)b * 16384;
    const half8* VfB = (const half8*)Vf + (size_t)b * 16384;  // 64 tiles * 256

    // Q fragments from fragment-major tiles (kA-pattern indices)
    const half8* qtA = QfB + (size_t)(4 * tile + 0) * 128;
    const half8* qtB = QfB + (size_t)(4 * tile + 1) * 128;
    const half8* qtC = QfB + (size_t)(4 * tile + 2) * 128;
    const half8* qtD = QfB + (size_t)(4 * tile + 3) * 128;
    const half8 qA0 = qtA[g * 16 + ql], qA1 = qtA[(4 + g) * 16 + ql];
    const half8 qB0 = qtB[g * 16 + ql], qB1 = qtB[(4 + g) * 16 + ql];
    const half8 qC0 = qtC[g * 16 + ql], qC1 = qtC[(4 + g) * 16 + ql];
    const half8 qD0 = qtD[g * 16 + ql], qD1 = qtD[(4 + g) * 16 + ql];

    const f32x4 z4 = {0.f, 0.f, 0.f, 0.f};
    f32x4 aA0 = z4, aA1 = z4, aA2 = z4, aA3 = z4;
    f32x4 aB0 = z4, aB1 = z4, aB2 = z4, aB3 = z4;
    f32x4 aC0 = z4, aC1 = z4, aC2 = z4, aC3 = z4;
    f32x4 aD0 = z4, aD1 = z4, aD2 = z4, aD3 = z4;
    float mA = -1e30f, lsA = 0.f;
    float mB = -1e30f, lsB = 0.f;
    float mC = -1e30f, lsC = 0.f;
    float mD = -1e30f, lsD = 0.f;

    const int kb0 = wid << 8;                    // 256 keys per split
    const half8* kA = KfB + (size_t)(kb0 >> 4) * 128 + g * 16 + ql;
    const half8* vA = VfB + (size_t)(kb0 >> 5) * 256 + ql * 4 + g;

    // ---- prologue: load iteration 0's fragments ----
    half8 k0lo = kA[0];
    half8 k0hi = kA[64];
    half8 k1lo = kA[128];
    half8 k1hi = kA[192];
    half8 v0 = vA[0];
    half8 v1 = vA[64];
    half8 v2 = vA[128];
    half8 v3 = vA[192];

    for (int it = 0; it < 8; ++it) {
        half8 nk0lo, nk0hi, nk1lo, nk1hi, nv0, nv1, nv2, nv3;
        if (it < 7) {
            nk0lo = kA[256];
            nk0hi = kA[256 + 64];
            nk1lo = kA[256 + 128];
            nk1hi = kA[256 + 192];
            nv0 = vA[256];
            nv1 = vA[256 + 64];
            nv2 = vA[256 + 128];
            nv3 = vA[256 + 192];
        }

        PROC(qA0, qA1, aA0, aA1, aA2, aA3, mA, lsA);
        PROC(qB0, qB1, aB0, aB1, aB2, aB3, mB, lsB);
        PROC(qC0, qC1, aC0, aC1, aC2, aC3, mC, lsC);
        PROC(qD0, qD1, aD0, aD1, aD2, aD3, mD, lsD);

        if (it < 7) {
            k0lo = nk0lo; k0hi = nk0hi; k1lo = nk1lo; k1hi = nk1hi;
            v0 = nv0; v1 = nv1; v2 = nv2; v3 = nv3;
        }
        kA += 256;
        vA += 256;
    }

    // ---- reduce per-lane lsum partials across the 4 lane-groups ----
    lsA += __shfl_xor(lsA, 16); lsA += __shfl_xor(lsA, 32);
    lsB += __shfl_xor(lsB, 16); lsB += __shfl_xor(lsB, 32);
    lsC += __shfl_xor(lsC, 16); lsC += __shfl_xor(lsC, 32);
    lsD += __shfl_xor(lsD, 16); lsD += __shfl_xor(lsD, 32);

    // ---- write partials to LDS: rows 0..15=A, 16..31=B, 32..47=C, 48..63=D
#pragma unroll
    for (int r = 0; r < 4; ++r) {
        Ol[wid][     4 * g + r][ 0 + ql] = aA0[r];
        Ol[wid][     4 * g + r][16 + ql] = aA1[r];
        Ol[wid][     4 * g + r][32 + ql] = aA2[r];
        Ol[wid][     4 * g + r][48 + ql] = aA3[r];
        Ol[wid][16 + 4 * g + r][ 0 + ql] = aB0[r];
        Ol[wid][16 + 4 * g + r][16 + ql] = aB1[r];
        Ol[wid][16 + 4 * g + r][32 + ql] = aB2[r];
        Ol[wid][16 + 4 * g + r][48 + ql] = aB3[r];
        Ol[wid][32 + 4 * g + r][ 0 + ql] = aC0[r];
        Ol[wid][32 + 4 * g + r][16 + ql] = aC1[r];
        Ol[wid][32 + 4 * g + r][32 + ql] = aC2[r];
        Ol[wid][32 + 4 * g + r][48 + ql] = aC3[r];
        Ol[wid][48 + 4 * g + r][ 0 + ql] = aD0[r];
        Ol[wid][48 + 4 * g + r][16 + ql] = aD1[r];
        Ol[wid][48 + 4 * g + r][32 + ql] = aD2[r];
        Ol[wid][48 + 4 * g + r][48 + ql] = aD3[r];
    }
    if (g == 0) {
        Ml[wid][     ql] = mA;  Ll[wid][     ql] = lsA;
        Ml[wid][16 + ql] = mB;  Ll[wid][16 + ql] = lsB;
        Ml[wid][32 + ql] = mC;  Ll[wid][32 + ql] = lsC;
        Ml[wid][48 + ql] = mD;  Ll[wid][48 + ql] = lsD;
    }
    __syncthreads();

    // ---- combine 8 key-splits; 512 threads, one (row, 8-col chunk) each ----
    const int tid = threadIdx.x;
    const int qq  = tid >> 3;                    // 0..63 row within block
    const int d0  = (tid & 7) * 8;

    float mm[8], lv[8];
#pragma unroll
    for (int s = 0; s < 8; ++s) {
        mm[s] = Ml[s][qq];
        lv[s] = Ll[s][qq];
    }
    float ms = mm[0];
#pragma unroll
    for (int s = 1; s < 8; ++s) ms = fmaxf(ms, mm[s]);
    float lt = 0.f;
    f32x4 oa = {0.f, 0.f, 0.f, 0.f};
    f32x4 ob2 = {0.f, 0.f, 0.f, 0.f};
#pragma unroll
    for (int s = 0; s < 8; ++s) {
        const float sc = xexp2(mm[s] - ms);
        lt += lv[s] * sc;
        oa  += *(const f32x4*)(&Ol[s][qq][d0])     * sc;
        ob2 += *(const f32x4*)(&Ol[s][qq][d0 + 4]) * sc;
    }
    const float inv = 1.0f / lt;
    const size_t grow = (size_t)b * T_ + (tile << 6) + qq;
    const f32x4 fr0 = *(const f32x4*)(F + grow * 64 + d0);
    const f32x4 fr1 = *(const f32x4*)(F + grow * 64 + d0 + 4);
    *(f32x4*)(out + grow * 64 + d0)     = oa * inv + fr0;
    *(f32x4*)(out + grow * 64 + d0 + 4) = ob2 * inv + fr1;
}

extern "C" void kernel_launch(void* const* d_in, const int* in_sizes, int n_in,
                              void* d_out, int out_size, void* d_ws, size_t ws_size,
                              hipStream_t stream)
{
    const float* F  = (const float*)d_in[0];
    const float* WM = (const float*)d_in[1];
    const float* WN = (const float*)d_in[2];
    const float* WV = (const float*)d_in[3];
    float* out = (float*)d_out;

    const size_t proj_bytes = (size_t)B_ * T_ * 64 * sizeof(_Float16); // 2 MB
    char* ws = (char*)d_ws;
    _Float16* Qf = (_Float16*)(ws);
    _Float16* Kf = (_Float16*)(ws + proj_bytes);
    _Float16* Vf = (_Float16*)(ws + 2 * proj_bytes);
    _Float16* Wp = (_Float16*)(ws + 3 * proj_bytes);  // 3*64*64 f16 = 24 KB

    hipLaunchKernelGGL(prepack_kernel, dim3(48), dim3(256), 0, stream,
                       WM, WN, WV, Wp);
    hipLaunchKernelGGL(proj_kernel, dim3(B_ * T_ / 16), dim3(256), 0, stream,
                       F, Wp, Qf, Kf, Vf);
    hipLaunchKernelGGL(attn_kernel, dim3(B_ * T_ / 64), dim3(512), 0, stream,
                       Qf, Kf, Vf, F, out);
}

// Round 14
// 26.412 us; speedup vs baseline: 1.2278x; 1.2278x over previous
//
#include <hip/hip_runtime.h>
#include <hip/hip_bf16.h>

// Problem constants (fixed by reference): B=8, T=2048, C=64
#define B_ 8
#define T_ 2048
#define LOG2E 1.4426950408889634f

typedef _Float16 half8 __attribute__((ext_vector_type(8)));
typedef _Float16 half4 __attribute__((ext_vector_type(4)));
typedef float f32x4 __attribute__((ext_vector_type(4)));

#define MFMA16(A, Bv, Cv) __builtin_amdgcn_mfma_f32_16x16x32_f16((A), (Bv), (Cv), 0, 0, 0)

__device__ inline float xexp2(float x)
{
    float r;
    asm("v_exp_f32 %0, %1" : "=v"(r) : "v"(x));
    return r;
}

// ---------------------------------------------------------------------------
// Kernel 1: MFMA projections -> fragment-major Q/K/V layouts (R13-verified
// layouts/stores). PREPACK FUSED: W fragments are loaded directly from the
// fp32 weights with on-the-fly f16 convert. Thread (ql,g,dt) needs
// W[k][d] for d = dt*16+ql, k = 8g..8g+7 (+32) -- identical elements the
// old Wp[mat][d][k] path delivered (W is 48 KB, L1-hot after first block).
// Removes the prepack dispatch + drain entirely.
// ---------------------------------------------------------------------------
__global__ __launch_bounds__(256) void proj_kernel(
    const float* __restrict__ F, const float* __restrict__ WM,
    const float* __restrict__ WN, const float* __restrict__ WV,
    _Float16* __restrict__ Qf, _Float16* __restrict__ Kf,
    _Float16* __restrict__ Vf)
{
    const int lane = threadIdx.x & 63;
    const int dt   = threadIdx.x >> 6;            // 0..3 = d-tile
    const int ql = lane & 15;
    const int g  = lane >> 4;
    const int blk = blockIdx.x;                   // 0..1023
    const int b   = blk & 7;                      // XCD-affine batch
    const int rt  = blk >> 3;                     // 0..127 row-tile in batch
    const int rowbase = b * T_ + rt * 16;
    const int d = dt * 16 + ql;

    // ---- F fragments ----
    const float* fr = F + (size_t)(rowbase + ql) * 64;
    const f32x4 v00 = *(const f32x4*)(fr + 8 * g);
    const f32x4 v01 = *(const f32x4*)(fr + 8 * g + 4);
    const f32x4 v10 = *(const f32x4*)(fr + 32 + 8 * g);
    const f32x4 v11 = *(const f32x4*)(fr + 32 + 8 * g + 4);
    half8 af0, af1;
#pragma unroll
    for (int j = 0; j < 4; ++j) {
        af0[j]     = (_Float16)v00[j];
        af0[4 + j] = (_Float16)v01[j];
        af1[j]     = (_Float16)v10[j];
        af1[4 + j] = (_Float16)v11[j];
    }

    // ---- W fragments, direct from fp32 (inline prepack) ----
    half8 wq0, wq1, wk0, wk1, wv0, wv1;
#pragma unroll
    for (int j = 0; j < 8; ++j) {
        const int k0 = (8 * g + j) * 64 + d;
        const int k1 = (32 + 8 * g + j) * 64 + d;
        wq0[j] = (_Float16)WM[k0];
        wq1[j] = (_Float16)WM[k1];
        wk0[j] = (_Float16)WN[k0];
        wk1[j] = (_Float16)WN[k1];
        wv0[j] = (_Float16)WV[k0];
        wv1[j] = (_Float16)WV[k1];
    }

    f32x4 z = {0.f, 0.f, 0.f, 0.f};
    // Q, K swapped: lane = t (row), regs = d
    f32x4 accQ = MFMA16(wq0, af0, z);
    accQ = MFMA16(wq1, af1, accQ);
    f32x4 accK = MFMA16(wk0, af0, z);
    accK = MFMA16(wk1, af1, accK);
    // V unswapped: lane = d, regs = key
    f32x4 accV = MFMA16(af0, wv0, z);
    accV = MFMA16(af1, wv1, accV);

    const int d0 = dt * 16 + 4 * g;
    const int p  = ((d0 >> 5) << 2) | ((d0 >> 3) & 3);
    const size_t tbase = (((size_t)b * 128 + rt) * 8 + p) * 128 + ql * 8 + (d0 & 7);
    {
        half4 qs;
#pragma unroll
        for (int r = 0; r < 4; ++r) qs[r] = (_Float16)(accQ[r] * LOG2E);
        *(half4*)(Qf + tbase) = qs;
    }
    {
        half4 ks;
#pragma unroll
        for (int r = 0; r < 4; ++r) ks[r] = (_Float16)accK[r];
        *(half4*)(Kf + tbase) = ks;
    }
    {
        half4 vs;
#pragma unroll
        for (int r = 0; r < 4; ++r) vs[r] = (_Float16)accV[r];
        const int kt5 = rt >> 1;
        const int cp0 = 8 * g + 4 * (rt & 1);
        *(half4*)(Vf + ((((size_t)b * 64 + kt5) * 4 + dt) * 16 + ql) * 32 + cp0) = vs;
    }
}

// Softmax + PV for one q-tile, given precomputed scores s0,s1
// (R10-R13-verified arithmetic; QK^T hoisted out for stage clustering).
#define SM(s0, s1, a0, a1, a2, a3, mr, ls)                                   \
    do {                                                                     \
        const float p0 = s0[0], p1 = s0[1], p2 = s0[2], p3 = s0[3];          \
        const float p4 = s1[0], p5 = s1[1], p6 = s1[2], p7 = s1[3];          \
        const float q0_ = fmaxf(fmaxf(p0, p1), p2);                          \
        const float q1_ = fmaxf(fmaxf(p3, p4), p5);                          \
        const float q2_ = fmaxf(fmaxf(p6, p7), q0_);                         \
        const float pm  = fmaxf(q1_, q2_);                                   \
        if (__any(pm - mr > 8.0f)) {                                         \
            float pmw = fmaxf(pm, __shfl_xor(pm, 16));                       \
            pmw = fmaxf(pmw, __shfl_xor(pmw, 32));                           \
            const float mnew = fmaxf(mr, pmw);                               \
            const float fac  = xexp2(mr - mnew);                             \
            mr = mnew;                                                       \
            ls *= fac;                                                       \
            const int lg = 4 * ((threadIdx.x & 63) >> 4);                    \
            const int lb = (threadIdx.x & 48);                               \
            const float f0 = __shfl(fac, lb | (lg + 0));                     \
            const float f1 = __shfl(fac, lb | (lg + 1));                     \
            const float f2 = __shfl(fac, lb | (lg + 2));                     \
            const float f3 = __shfl(fac, lb | (lg + 3));                     \
            a0[0] *= f0; a0[1] *= f1; a0[2] *= f2; a0[3] *= f3;              \
            a1[0] *= f0; a1[1] *= f1; a1[2] *= f2; a1[3] *= f3;              \
            a2[0] *= f0; a2[1] *= f1; a2[2] *= f2; a2[3] *= f3;              \
            a3[0] *= f0; a3[1] *= f1; a3[2] *= f2; a3[3] *= f3;              \
        }                                                                    \
        const float e0 = xexp2(p0 - mr), e1 = xexp2(p1 - mr);                \
        const float e2 = xexp2(p2 - mr), e3 = xexp2(p3 - mr);                \
        const float e4 = xexp2(p4 - mr), e5 = xexp2(p5 - mr);                \
        const float e6 = xexp2(p6 - mr), e7 = xexp2(p7 - mr);                \
        ls += ((e0 + e1) + (e2 + e3)) + ((e4 + e5) + (e6 + e7));             \
        half8 pav;                                                           \
        pav[0] = (_Float16)e0; pav[1] = (_Float16)e1;                        \
        pav[2] = (_Float16)e2; pav[3] = (_Float16)e3;                        \
        pav[4] = (_Float16)e4; pav[5] = (_Float16)e5;                        \
        pav[6] = (_Float16)e6; pav[7] = (_Float16)e7;                        \
        a0 = MFMA16(pav, v0, a0);                                            \
        a1 = MFMA16(pav, v1, a1);                                            \
        a2 = MFMA16(pav, v2, a2);                                            \
        a3 = MFMA16(pav, v3, a3);                                            \
    } while (0)

// ---------------------------------------------------------------------------
// Kernel 2: flash attention, STAGE-CLUSTERED inner loop. R13 structure
// (block = 64 q-rows, 8 waves, wave = 4 q-tiles x 256-key split, register
// prefetch), but all 16 QK^T MFMAs are issued back-to-back BEFORE any
// softmax branch: the per-tile `if(__any)` branches previously fenced the
// scheduler so the 4 tiles' MFMA chains never interleaved (R10-R13's
// ~940 cyc/PROC vs ~250 critical path). 8 independent 2-chains fill the
// MFMA pipe; softmax sections then overlap PV via the same clustering.
// ---------------------------------------------------------------------------
__global__ __launch_bounds__(512, 1) void attn_kernel(
    const _Float16* __restrict__ Qf, const _Float16* __restrict__ Kf,
    const _Float16* __restrict__ Vf, const float* __restrict__ F,
    float* __restrict__ out)
{
    __shared__ float Ol[8][64][68];    // 139 KB: [split][row][d]
    __shared__ float Ml[8][64];
    __shared__ float Ll[8][64];

    const int lane = threadIdx.x & 63;
    const int wid  = threadIdx.x >> 6;           // 0..7 = key-split
    const int blk  = blockIdx.x;                 // 0..255
    const int b    = blk & 7;                    // XCD-affine batch
    const int tile = blk >> 3;                   // 0..31
    const int ql = lane & 15;
    const int g  = lane >> 4;

    const half8* QfB = (const half8*)Qf + (size_t)b * 16384;  // 128 tiles * 128
    const half8* KfB = (const half8*)Kf + (size_t)b * 16384;
    const half8* VfB = (const half8*)Vf + (size_t)b * 16384;  // 64 tiles * 256

    const half8* qtA = QfB + (size_t)(4 * tile + 0) * 128;
    const half8* qtB = QfB + (size_t)(4 * tile + 1) * 128;
    const half8* qtC = QfB + (size_t)(4 * tile + 2) * 128;
    const half8* qtD = QfB + (size_t)(4 * tile + 3) * 128;
    const half8 qA0 = qtA[g * 16 + ql], qA1 = qtA[(4 + g) * 16 + ql];
    const half8 qB0 = qtB[g * 16 + ql], qB1 = qtB[(4 + g) * 16 + ql];
    const half8 qC0 = qtC[g * 16 + ql], qC1 = qtC[(4 + g) * 16 + ql];
    const half8 qD0 = qtD[g * 16 + ql], qD1 = qtD[(4 + g) * 16 + ql];

    const f32x4 z4 = {0.f, 0.f, 0.f, 0.f};
    f32x4 aA0 = z4, aA1 = z4, aA2 = z4, aA3 = z4;
    f32x4 aB0 = z4, aB1 = z4, aB2 = z4, aB3 = z4;
    f32x4 aC0 = z4, aC1 = z4, aC2 = z4, aC3 = z4;
    f32x4 aD0 = z4, aD1 = z4, aD2 = z4, aD3 = z4;
    float mA = -1e30f, lsA = 0.f;
    float mB = -1e30f, lsB = 0.f;
    float mC = -1e30f, lsC = 0.f;
    float mD = -1e30f, lsD = 0.f;

    const int kb0 = wid << 8;                    // 256 keys per split
    const half8* kA = KfB + (size_t)(kb0 >> 4) * 128 + g * 16 + ql;
    const half8* vA = VfB + (size_t)(kb0 >> 5) * 256 + ql * 4 + g;

    half8 k0lo = kA[0];
    half8 k0hi = kA[64];
    half8 k1lo = kA[128];
    half8 k1hi = kA[192];
    half8 v0 = vA[0];
    half8 v1 = vA[64];
    half8 v2 = vA[128];
    half8 v3 = vA[192];

    for (int it = 0; it < 8; ++it) {
        half8 nk0lo, nk0hi, nk1lo, nk1hi, nv0, nv1, nv2, nv3;
        if (it < 7) {
            nk0lo = kA[256];
            nk0hi = kA[256 + 64];
            nk1lo = kA[256 + 128];
            nk1hi = kA[256 + 192];
            nv0 = vA[256];
            nv1 = vA[256 + 64];
            nv2 = vA[256 + 128];
            nv3 = vA[256 + 192];
        }

        // ---- QK^T phase: 16 MFMAs, 8 independent 2-chains, no branches ----
        f32x4 sA0 = z4, sA1 = z4, sB0 = z4, sB1 = z4;
        f32x4 sC0 = z4, sC1 = z4, sD0 = z4, sD1 = z4;
        sA0 = MFMA16(k0lo, qA0, sA0);
        sB0 = MFMA16(k0lo, qB0, sB0);
        sC0 = MFMA16(k0lo, qC0, sC0);
        sD0 = MFMA16(k0lo, qD0, sD0);
        sA1 = MFMA16(k1lo, qA0, sA1);
        sB1 = MFMA16(k1lo, qB0, sB1);
        sC1 = MFMA16(k1lo, qC0, sC1);
        sD1 = MFMA16(k1lo, qD0, sD1);
        sA0 = MFMA16(k0hi, qA1, sA0);
        sB0 = MFMA16(k0hi, qB1, sB0);
        sC0 = MFMA16(k0hi, qC1, sC0);
        sD0 = MFMA16(k0hi, qD1, sD0);
        sA1 = MFMA16(k1hi, qA1, sA1);
        sB1 = MFMA16(k1hi, qB1, sB1);
        sC1 = MFMA16(k1hi, qC1, sC1);
        sD1 = MFMA16(k1hi, qD1, sD1);

        // ---- softmax + PV phase, per tile ----
        SM(sA0, sA1, aA0, aA1, aA2, aA3, mA, lsA);
        SM(sB0, sB1, aB0, aB1, aB2, aB3, mB, lsB);
        SM(sC0, sC1, aC0, aC1, aC2, aC3, mC, lsC);
        SM(sD0, sD1, aD0, aD1, aD2, aD3, mD, lsD);

        if (it < 7) {
            k0lo = nk0lo; k0hi = nk0hi; k1lo = nk1lo; k1hi = nk1hi;
            v0 = nv0; v1 = nv1; v2 = nv2; v3 = nv3;
        }
        kA += 256;
        vA += 256;
    }

    // ---- reduce per-lane lsum partials across the 4 lane-groups ----
    lsA += __shfl_xor(lsA, 16); lsA += __shfl_xor(lsA, 32);
    lsB += __shfl_xor(lsB, 16); lsB += __shfl_xor(lsB, 32);
    lsC += __shfl_xor(lsC, 16); lsC += __shfl_xor(lsC, 32);
    lsD += __shfl_xor(lsD, 16); lsD += __shfl_xor(lsD, 32);

    // ---- write partials to LDS: rows 0..15=A, 16..31=B, 32..47=C, 48..63=D
#pragma unroll
    for (int r = 0; r < 4; ++r) {
        Ol[wid][     4 * g + r][ 0 + ql] = aA0[r];
        Ol[wid][     4 * g + r][16 + ql] = aA1[r];
        Ol[wid][     4 * g + r][32 + ql] = aA2[r];
        Ol[wid][     4 * g + r][48 + ql] = aA3[r];
        Ol[wid][16 + 4 * g + r][ 0 + ql] = aB0[r];
        Ol[wid][16 + 4 * g + r][16 + ql] = aB1[r];
        Ol[wid][16 + 4 * g + r][32 + ql] = aB2[r];
        Ol[wid][16 + 4 * g + r][48 + ql] = aB3[r];
        Ol[wid][32 + 4 * g + r][ 0 + ql] = aC0[r];
        Ol[wid][32 + 4 * g + r][16 + ql] = aC1[r];
        Ol[wid][32 + 4 * g + r][32 + ql] = aC2[r];
        Ol[wid][32 + 4 * g + r][48 + ql] = aC3[r];
        Ol[wid][48 + 4 * g + r][ 0 + ql] = aD0[r];
        Ol[wid][48 + 4 * g + r][16 + ql] = aD1[r];
        Ol[wid][48 + 4 * g + r][32 + ql] = aD2[r];
        Ol[wid][48 + 4 * g + r][48 + ql] = aD3[r];
    }
    if (g == 0) {
        Ml[wid][     ql] = mA;  Ll[wid][     ql] = lsA;
        Ml[wid][16 + ql] = mB;  Ll[wid][16 + ql] = lsB;
        Ml[wid][32 + ql] = mC;  Ll[wid][32 + ql] = lsC;
        Ml[wid][48 + ql] = mD;  Ll[wid][48 + ql] = lsD;
    }
    __syncthreads();

    // ---- combine 8 key-splits; 512 threads, one (row, 8-col chunk) each ----
    const int tid = threadIdx.x;
    const int qq  = tid >> 3;                    // 0..63 row within block
    const int d0  = (tid & 7) * 8;

    float mm[8], lv[8];
#pragma unroll
    for (int s = 0; s < 8; ++s) {
        mm[s] = Ml[s][qq];
        lv[s] = Ll[s][qq];
    }
    float ms = mm[0];
#pragma unroll
    for (int s = 1; s < 8; ++s) ms = fmaxf(ms, mm[s]);
    float lt = 0.f;
    f32x4 oa = {0.f, 0.f, 0.f, 0.f};
    f32x4 ob2 = {0.f, 0.f, 0.f, 0.f};
#pragma unroll
    for (int s = 0; s < 8; ++s) {
        const float sc = xexp2(mm[s] - ms);
        lt += lv[s] * sc;
        oa  += *(const f32x4*)(&Ol[s][qq][d0])     * sc;
        ob2 += *(const f32x4*)(&Ol[s][qq][d0 + 4]) * sc;
    }
    const float inv = 1.0f / lt;
    const size_t grow = (size_t)b * T_ + (tile << 6) + qq;
    const f32x4 fr0 = *(const f32x4*)(F + grow * 64 + d0);
    const f32x4 fr1 = *(const f32x4*)(F + grow * 64 + d0 + 4);
    *(f32x4*)(out + grow * 64 + d0)     = oa * inv + fr0;
    *(f32x4*)(out + grow * 64 + d0 + 4) = ob2 * inv + fr1;
}

extern "C" void kernel_launch(void* const* d_in, const int* in_sizes, int n_in,
                              void* d_out, int out_size, void* d_ws, size_t ws_size,
                              hipStream_t stream)
{
    const float* F  = (const float*)d_in[0];
    const float* WM = (const float*)d_in[1];
    const float* WN = (const float*)d_in[2];
    const float* WV = (const float*)d_in[3];
    float* out = (float*)d_out;

    const size_t proj_bytes = (size_t)B_ * T_ * 64 * sizeof(_Float16); // 2 MB
    char* ws = (char*)d_ws;
    _Float16* Qf = (_Float16*)(ws);
    _Float16* Kf = (_Float16*)(ws + proj_bytes);
    _Float16* Vf = (_Float16*)(ws + 2 * proj_bytes);

    hipLaunchKernelGGL(proj_kernel, dim3(B_ * T_ / 16), dim3(256), 0, stream,
                       F, WM, WN, WV, Qf, Kf, Vf);
    hipLaunchKernelGGL(attn_kernel, dim3(B_ * T_ / 64), dim3(512), 0, stream,
                       Qf, Kf, Vf, F, out);
}